// Round 1
// baseline (407.782 us; speedup 1.0000x reference)
//
#include <hip/hip_runtime.h>
#include <hip/hip_bf16.h>

// Problem constants (reference): F=64, S=8192, D=128, W=128, MAX_SEQ=8192, ALPHA=0.1
#define NF 64
#define NS 8192
#define ND 128
#define NW 128
#define NK3 384          // 3*W
#define TKEEP 128        // EMA weights below 0.9^128*~1 ~ 1.4e-6 -> negligible
#define SBASE (NS - TKEEP)

typedef __attribute__((ext_vector_type(4))) float f32x4;
typedef __attribute__((ext_vector_type(8))) short bf16x8;

__device__ __forceinline__ short f2bf(float x) {
    union { float f; unsigned u; } v; v.f = x;
    unsigned r = v.u + 0x7FFFu + ((v.u >> 16) & 1u);  // RNE
    return (short)(r >> 16);
}
__device__ __forceinline__ float bf2f(short b) {
    union { float f; unsigned u; } v;
    v.u = ((unsigned)(unsigned short)b) << 16;
    return v.f;
}
// sin(2*pi*t) via v_sin_f32 (input in revolutions, fract-reduced)
__device__ __forceinline__ float sin2pi(float t) {
    return __builtin_amdgcn_sinf(t - floorf(t));
}

// ---------------- Stage A ----------------
// Per field: deltas[s,k] = sum_d kv[S-128+s,d]*Wenc[k,d]  (hi/lo bf16 split, 3 MFMA passes)
// then weighted reduce over s with w[s]=0.1*0.9^(127-s_loc), nonlinearity per k-range.
// Also converts Wdec -> bf16 in MFMA B-fragment order into ws.
__global__ __launch_bounds__(256) void wf_stage_a(
    const float* __restrict__ kv,      // [F][S][D]
    const float* __restrict__ Wenc,    // [F][384][128]
    const float* __restrict__ Wdec,    // [F][128][128]
    const float* __restrict__ bfreq,   // [F][128]
    float* __restrict__ wpar,          // [3][F][128]: ffn(=freqs+base), amp, phr(=phases/2pi)
    short* __restrict__ wdf)           // [F][8 nt][4 ks][64 lane][8] bf16
{
    const int f    = blockIdx.x;
    const int kb   = blockIdx.y;       // 0..2 : which 8 n-tiles of 24
    const int tid  = threadIdx.x;
    const int lane = tid & 63;
    const int wv   = tid >> 6;
    const int rgrp = lane >> 4;
    const int rlo  = lane & 15;

    __shared__ short kvhi[TKEEP * ND];
    __shared__ short kvlo[TKEEP * ND];
    __shared__ float wgt[TKEEP];

    // Part 0: Wdec fp32 -> bf16 fragment-ordered chunks (each block does 1/3)
    #pragma unroll
    for (int i = 0; i < 3; ++i) {
        int c = tid + 256 * (3 * i + kb);
        if (c < 2048) {
            int nt = c >> 8;
            int ks = (c >> 6) & 3;
            int ln = c & 63;
            int row = nt * 16 + (ln & 15);          // d
            int col = ks * 32 + ((ln >> 4) << 3);   // w
            const float* src = Wdec + ((size_t)f * ND + row) * NW + col;
            f32x4 a = *(const f32x4*)src;
            f32x4 b = *(const f32x4*)(src + 4);
            bf16x8 p;
            p[0] = f2bf(a[0]); p[1] = f2bf(a[1]); p[2] = f2bf(a[2]); p[3] = f2bf(a[3]);
            p[4] = f2bf(b[0]); p[5] = f2bf(b[1]); p[6] = f2bf(b[2]); p[7] = f2bf(b[3]);
            *(bf16x8*)(wdf + ((size_t)f * 2048 + c) * 8) = p;
        }
    }

    // Part 1: stage last 128 kv rows as hi/lo bf16, XOR-swizzled LDS
    {
        int c   = tid & 15;     // d-chunk of 8
        int sr0 = tid >> 4;     // 0..15
        #pragma unroll
        for (int r = 0; r < 8; ++r) {
            int s = sr0 + 16 * r;
            const float* src = kv + ((size_t)f * NS + SBASE + s) * ND + c * 8;
            f32x4 a = *(const f32x4*)src;
            f32x4 b = *(const f32x4*)(src + 4);
            bf16x8 hi, lo;
            #pragma unroll
            for (int j = 0; j < 4; ++j) {
                short h = f2bf(a[j]); hi[j] = h; lo[j] = f2bf(a[j] - bf2f(h));
            }
            #pragma unroll
            for (int j = 0; j < 4; ++j) {
                short h = f2bf(b[j]); hi[4 + j] = h; lo[4 + j] = f2bf(b[j] - bf2f(h));
            }
            int ofs = s * ND + ((c * 8) ^ ((s & 7) << 3));
            *(bf16x8*)(kvhi + ofs) = hi;
            *(bf16x8*)(kvlo + ofs) = lo;
        }
        if (tid < TKEEP)
            wgt[tid] = 0.1f * expf((float)(TKEEP - 1 - tid) * (-0.10536051565782628f));
    }
    __syncthreads();

    // Part 2: MFMA GEMM + nonlinear weighted reduce over s
    #pragma unroll
    for (int j = 0; j < 2; ++j) {
        int nt = kb * 8 + wv * 2 + j;    // 0..23
        int n0 = nt * 16;
        int kg = n0 + rlo;               // global k column (0..383)
        f32x4 acc[8];
        #pragma unroll
        for (int m = 0; m < 8; ++m) acc[m] = (f32x4){0.f, 0.f, 0.f, 0.f};

        for (int ks = 0; ks < 4; ++ks) {
            const float* srcW = Wenc + ((size_t)f * NK3 + kg) * ND + ks * 32 + rgrp * 8;
            f32x4 wa = *(const f32x4*)srcW;
            f32x4 wb = *(const f32x4*)(srcW + 4);
            bf16x8 bhi, blo;
            #pragma unroll
            for (int q = 0; q < 4; ++q) {
                short h = f2bf(wa[q]); bhi[q] = h; blo[q] = f2bf(wa[q] - bf2f(h));
            }
            #pragma unroll
            for (int q = 0; q < 4; ++q) {
                short h = f2bf(wb[q]); bhi[4 + q] = h; blo[4 + q] = f2bf(wb[q] - bf2f(h));
            }
            int colBase = ks * 32 + rgrp * 8;
            #pragma unroll
            for (int m = 0; m < 8; ++m) {
                int row = m * 16 + rlo;
                int ofs = row * ND + (colBase ^ ((row & 7) << 3));
                bf16x8 ahi = *(const bf16x8*)(kvhi + ofs);
                bf16x8 alo = *(const bf16x8*)(kvlo + ofs);
                acc[m] = __builtin_amdgcn_mfma_f32_16x16x32_bf16(ahi, bhi, acc[m], 0, 0, 0);
                acc[m] = __builtin_amdgcn_mfma_f32_16x16x32_bf16(alo, bhi, acc[m], 0, 0, 0);
                acc[m] = __builtin_amdgcn_mfma_f32_16x16x32_bf16(ahi, blo, acc[m], 0, 0, 0);
            }
        }

        float bfv = (nt < 8) ? bfreq[f * NW + kg] : 0.f;
        float psum = 0.f;
        #pragma unroll
        for (int m = 0; m < 8; ++m) {
            #pragma unroll
            for (int r = 0; r < 4; ++r) {
                int sl = m * 16 + rgrp * 4 + r;   // C/D layout: row=(lane>>4)*4+reg
                float v = acc[m][r];
                if (nt < 8) {                      // freq: * pos_signal
                    float posn = (float)(SBASE + sl) * (1.0f / 8192.0f);
                    v *= sin2pi(bfv * posn);
                } else if (nt < 16) {              // amp: abs
                    v = fabsf(v);
                }
                psum += v * wgt[sl];
            }
        }
        psum += __shfl_xor(psum, 16);
        psum += __shfl_xor(psum, 32);
        if (rgrp == 0) {
            if (nt < 8)       wpar[f * NW + kg] = psum + bfv;                       // ffn
            else if (nt < 16) wpar[8192 + f * NW + (kg - 128)] = psum;              // amp
            else              wpar[16384 + f * NW + (kg - 256)] = psum * 0.15915494309189535f; // phr
        }
    }
}

// ---------------- Stage B ----------------
// out[f,s,d] = sum_w amp*sin2pi(ffn*s/8192 + phr) * Wdec[d,w]; BM=128, BN=128(=D), K=128.
__global__ __launch_bounds__(256) void wf_stage_b(
    const float* __restrict__ wpar,
    const short* __restrict__ wdf,
    float* __restrict__ out)
{
    const int st   = blockIdx.x;     // s-tile (128 rows)
    const int f    = blockIdx.y;
    const int tid  = threadIdx.x;
    const int lane = tid & 63;
    const int wv   = tid >> 6;
    const int wr   = wv >> 1;        // wave row (s half)
    const int wc   = wv & 1;         // wave col (d half)
    const int rgrp = lane >> 4;
    const int rlo  = lane & 15;

    __shared__ short waveLDS[128 * NW];
    __shared__ float pLDS[384];

    if (tid < 96) {
        int a  = tid >> 5;
        int i4 = (tid & 31) * 4;
        *(f32x4*)&pLDS[a * 128 + i4] = *(const f32x4*)&wpar[a * 8192 + f * NW + i4];
    }
    __syncthreads();

    // compute wave-value tile [128 s][128 w] -> bf16, swizzled LDS
    {
        int srow = tid & 127;
        int half = tid >> 7;
        float posn = (float)(st * 128 + srow) * (1.0f / 8192.0f);
        #pragma unroll
        for (int c = 0; c < 8; ++c) {
            int w0 = half * 64 + c * 8;
            f32x4 fa = *(const f32x4*)&pLDS[w0];
            f32x4 fb = *(const f32x4*)&pLDS[w0 + 4];
            f32x4 aa = *(const f32x4*)&pLDS[128 + w0];
            f32x4 ab = *(const f32x4*)&pLDS[128 + w0 + 4];
            f32x4 pa = *(const f32x4*)&pLDS[256 + w0];
            f32x4 pb = *(const f32x4*)&pLDS[256 + w0 + 4];
            bf16x8 pk;
            #pragma unroll
            for (int j = 0; j < 4; ++j)
                pk[j] = f2bf(aa[j] * sin2pi(fa[j] * posn + pa[j]));
            #pragma unroll
            for (int j = 0; j < 4; ++j)
                pk[4 + j] = f2bf(ab[j] * sin2pi(fb[j] * posn + pb[j]));
            *(bf16x8*)&waveLDS[srow * NW + (w0 ^ ((srow & 7) << 3))] = pk;
        }
    }
    __syncthreads();

    f32x4 acc[4][4];
    #pragma unroll
    for (int mi = 0; mi < 4; ++mi)
        #pragma unroll
        for (int ni = 0; ni < 4; ++ni)
            acc[mi][ni] = (f32x4){0.f, 0.f, 0.f, 0.f};

    const short* wdfF = wdf + (size_t)f * 16384;
    #pragma unroll
    for (int ks = 0; ks < 4; ++ks) {
        bf16x8 bfr[4];
        #pragma unroll
        for (int ni = 0; ni < 4; ++ni) {
            int nt = wc * 4 + ni;
            bfr[ni] = *(const bf16x8*)(wdfF + ((size_t)((nt * 4 + ks) * 64 + lane)) * 8);
        }
        bf16x8 afr[4];
        #pragma unroll
        for (int mi = 0; mi < 4; ++mi) {
            int row = wr * 64 + mi * 16 + rlo;
            int col = ks * 32 + rgrp * 8;
            afr[mi] = *(const bf16x8*)&waveLDS[row * NW + (col ^ ((row & 7) << 3))];
        }
        #pragma unroll
        for (int mi = 0; mi < 4; ++mi)
            #pragma unroll
            for (int ni = 0; ni < 4; ++ni)
                acc[mi][ni] = __builtin_amdgcn_mfma_f32_16x16x32_bf16(afr[mi], bfr[ni], acc[mi][ni], 0, 0, 0);
    }

    size_t base = ((size_t)f * NS + (size_t)st * 128) * ND;
    #pragma unroll
    for (int mi = 0; mi < 4; ++mi) {
        #pragma unroll
        for (int r = 0; r < 4; ++r) {
            int sl = wr * 64 + mi * 16 + rgrp * 4 + r;
            float* dst = out + base + (size_t)sl * ND + wc * 64 + rlo;
            #pragma unroll
            for (int ni = 0; ni < 4; ++ni)
                dst[ni * 16] = acc[mi][ni][r];
        }
    }
}

extern "C" void kernel_launch(void* const* d_in, const int* in_sizes, int n_in,
                              void* d_out, int out_size, void* d_ws, size_t ws_size,
                              hipStream_t stream) {
    const float* kv    = (const float*)d_in[0];
    // d_in[1] = positions (arange, encoded analytically)
    const float* Wenc  = (const float*)d_in[2];
    const float* Wdec  = (const float*)d_in[3];
    const float* bfreq = (const float*)d_in[4];

    float* wpar = (float*)d_ws;                         // 3*64*128 floats = 96 KB
    short* wdf  = (short*)((char*)d_ws + 98304);        // 64*16384 bf16 = 2 MB

    wf_stage_a<<<dim3(NF, 3), 256, 0, stream>>>(kv, Wenc, Wdec, bfreq, wpar, wdf);
    wf_stage_b<<<dim3(NS / 128, NF), 256, 0, stream>>>(wpar, wdf, (float*)d_out);
}

// Round 2
// 403.314 us; speedup vs baseline: 1.0111x; 1.0111x over previous
//
#include <hip/hip_runtime.h>
#include <hip/hip_bf16.h>

// Problem constants (reference): F=64, S=8192, D=128, W=128, MAX_SEQ=8192, ALPHA=0.1
#define NF 64
#define NS 8192
#define ND 128
#define NW 128
#define NK3 384          // 3*W
#define TKEEP 128        // EMA weights below 0.9^128 ~ 1.4e-6 -> negligible
#define SBASE (NS - TKEEP)

typedef __attribute__((ext_vector_type(4))) float f32x4;
typedef __attribute__((ext_vector_type(8))) short bf16x8;

__device__ __forceinline__ short f2bf(float x) {
    union { float f; unsigned u; } v; v.f = x;
    unsigned r = v.u + 0x7FFFu + ((v.u >> 16) & 1u);  // RNE
    return (short)(r >> 16);
}
__device__ __forceinline__ float bf2f(short b) {
    union { float f; unsigned u; } v;
    v.u = ((unsigned)(unsigned short)b) << 16;
    return v.f;
}
// sin(2*pi*t) via v_sin_f32 (input in revolutions, fract-reduced)
__device__ __forceinline__ float sin2pi(float t) {
    return __builtin_amdgcn_sinf(t - floorf(t));
}

// ---------------- Wdec -> bf16 fragment-order conversion ----------------
// wdf layout: [F][8 nt][4 ks][64 lane][8] bf16  (B-fragment order for stage B)
__global__ __launch_bounds__(256) void wf_wdec(
    const float* __restrict__ Wdec,    // [F][128][128]
    short* __restrict__ wdf)
{
    const int f = blockIdx.x;
    const int c = blockIdx.y * 256 + threadIdx.x;   // 0..2047
    const int nt = c >> 8;
    const int ks = (c >> 6) & 3;
    const int ln = c & 63;
    const int row = nt * 16 + (ln & 15);            // d
    const int col = ks * 32 + ((ln >> 4) << 3);     // w
    const float* src = Wdec + ((size_t)f * ND + row) * NW + col;
    f32x4 a = *(const f32x4*)src;
    f32x4 b = *(const f32x4*)(src + 4);
    bf16x8 p;
    p[0] = f2bf(a[0]); p[1] = f2bf(a[1]); p[2] = f2bf(a[2]); p[3] = f2bf(a[3]);
    p[4] = f2bf(b[0]); p[5] = f2bf(b[1]); p[6] = f2bf(b[2]); p[7] = f2bf(b[3]);
    *(bf16x8*)(wdf + ((size_t)f * 2048 + c) * 8) = p;
}

// ---------------- Stage A ----------------
// Per field: deltas[s,k] = sum_d kv[S-128+s,d]*Wenc[k,d]  (hi/lo bf16 split, 3 MFMA passes)
// then weighted reduce over s with w[s]=0.1*0.9^(127-s_loc), nonlinearity per k-range.
// Grid (F, 6): each block covers 4 n-tiles (1 per wave). Wenc fragments are
// prefetched into registers BEFORE the staging barrier so their latency
// overlaps the kv LDS staging (single exposed latency, not 8 serial ones).
__global__ __launch_bounds__(256) void wf_stage_a(
    const float* __restrict__ kv,      // [F][S][D]
    const float* __restrict__ Wenc,    // [F][384][128]
    const float* __restrict__ bfreq,   // [F][128]
    float* __restrict__ wpar)          // [3][F][128]: ffn(=freqs+base), amp, phr(=phases/2pi)
{
    const int f    = blockIdx.x;
    const int kb   = blockIdx.y;       // 0..5
    const int tid  = threadIdx.x;
    const int lane = tid & 63;
    const int wv   = tid >> 6;
    const int rgrp = lane >> 4;
    const int rlo  = lane & 15;

    const int nt = kb * 4 + wv;        // 0..23
    const int kg = nt * 16 + rlo;      // global k row of Wenc (0..383)

    __shared__ short kvhi[TKEEP * ND];
    __shared__ short kvlo[TKEEP * ND];
    __shared__ float wgt[TKEEP];

    // Prefetch all Wenc fragments for this wave's n-tile (8 x 16B loads in flight)
    f32x4 wA[4], wB[4];
    #pragma unroll
    for (int ks = 0; ks < 4; ++ks) {
        const float* srcW = Wenc + ((size_t)f * NK3 + kg) * ND + ks * 32 + rgrp * 8;
        wA[ks] = *(const f32x4*)srcW;
        wB[ks] = *(const f32x4*)(srcW + 4);
    }

    // Stage last 128 kv rows as hi/lo bf16, XOR-swizzled LDS
    {
        int c   = tid & 15;     // d-chunk of 8
        int sr0 = tid >> 4;     // 0..15
        #pragma unroll
        for (int r = 0; r < 8; ++r) {
            int s = sr0 + 16 * r;
            const float* src = kv + ((size_t)f * NS + SBASE + s) * ND + c * 8;
            f32x4 a = *(const f32x4*)src;
            f32x4 b = *(const f32x4*)(src + 4);
            bf16x8 hi, lo;
            #pragma unroll
            for (int j = 0; j < 4; ++j) {
                short h = f2bf(a[j]); hi[j] = h; lo[j] = f2bf(a[j] - bf2f(h));
            }
            #pragma unroll
            for (int j = 0; j < 4; ++j) {
                short h = f2bf(b[j]); hi[4 + j] = h; lo[4 + j] = f2bf(b[j] - bf2f(h));
            }
            int ofs = s * ND + ((c * 8) ^ ((s & 7) << 3));
            *(bf16x8*)(kvhi + ofs) = hi;
            *(bf16x8*)(kvlo + ofs) = lo;
        }
        if (tid < TKEEP)
            wgt[tid] = 0.1f * expf((float)(TKEEP - 1 - tid) * (-0.10536051565782628f));
    }
    __syncthreads();

    // MFMA GEMM + nonlinear weighted reduce over s
    f32x4 acc[8];
    #pragma unroll
    for (int m = 0; m < 8; ++m) acc[m] = (f32x4){0.f, 0.f, 0.f, 0.f};

    #pragma unroll
    for (int ks = 0; ks < 4; ++ks) {
        bf16x8 bhi, blo;
        #pragma unroll
        for (int q = 0; q < 4; ++q) {
            short h = f2bf(wA[ks][q]); bhi[q] = h; blo[q] = f2bf(wA[ks][q] - bf2f(h));
        }
        #pragma unroll
        for (int q = 0; q < 4; ++q) {
            short h = f2bf(wB[ks][q]); bhi[4 + q] = h; blo[4 + q] = f2bf(wB[ks][q] - bf2f(h));
        }
        int colBase = ks * 32 + rgrp * 8;
        #pragma unroll
        for (int m = 0; m < 8; ++m) {
            int row = m * 16 + rlo;
            int ofs = row * ND + (colBase ^ ((row & 7) << 3));
            bf16x8 ahi = *(const bf16x8*)(kvhi + ofs);
            bf16x8 alo = *(const bf16x8*)(kvlo + ofs);
            acc[m] = __builtin_amdgcn_mfma_f32_16x16x32_bf16(ahi, bhi, acc[m], 0, 0, 0);
            acc[m] = __builtin_amdgcn_mfma_f32_16x16x32_bf16(alo, bhi, acc[m], 0, 0, 0);
            acc[m] = __builtin_amdgcn_mfma_f32_16x16x32_bf16(ahi, blo, acc[m], 0, 0, 0);
        }
    }

    float bfv = (nt < 8) ? bfreq[f * NW + kg] : 0.f;
    float psum = 0.f;
    #pragma unroll
    for (int m = 0; m < 8; ++m) {
        #pragma unroll
        for (int r = 0; r < 4; ++r) {
            int sl = m * 16 + rgrp * 4 + r;   // C/D layout: row=(lane>>4)*4+reg
            float v = acc[m][r];
            if (nt < 8) {                      // freq: * pos_signal
                float posn = (float)(SBASE + sl) * (1.0f / 8192.0f);
                v *= sin2pi(bfv * posn);
            } else if (nt < 16) {              // amp: abs
                v = fabsf(v);
            }
            psum += v * wgt[sl];
        }
    }
    psum += __shfl_xor(psum, 16);
    psum += __shfl_xor(psum, 32);
    if (rgrp == 0) {
        if (nt < 8)       wpar[f * NW + kg] = psum + bfv;                       // ffn
        else if (nt < 16) wpar[8192 + f * NW + (kg - 128)] = psum;              // amp
        else              wpar[16384 + f * NW + (kg - 256)] = psum * 0.15915494309189535f; // phr
    }
}

// ---------------- Stage B ----------------
// out[f,s,d] = sum_w amp*sin2pi(ffn*s/8192 + phr) * Wdec[d,w]; BM=128, BN=128(=D), K=128.
__global__ __launch_bounds__(256) void wf_stage_b(
    const float* __restrict__ wpar,
    const short* __restrict__ wdf,
    float* __restrict__ out)
{
    const int st   = blockIdx.x;     // s-tile (128 rows)
    const int f    = blockIdx.y;
    const int tid  = threadIdx.x;
    const int lane = tid & 63;
    const int wv   = tid >> 6;
    const int wr   = wv >> 1;        // wave row (s half)
    const int wc   = wv & 1;         // wave col (d half)
    const int rgrp = lane >> 4;
    const int rlo  = lane & 15;

    __shared__ short waveLDS[128 * NW];
    __shared__ float pLDS[384];

    if (tid < 96) {
        int a  = tid >> 5;
        int i4 = (tid & 31) * 4;
        *(f32x4*)&pLDS[a * 128 + i4] = *(const f32x4*)&wpar[a * 8192 + f * NW + i4];
    }
    __syncthreads();

    // compute wave-value tile [128 s][128 w] -> bf16, swizzled LDS
    {
        int srow = tid & 127;
        int half = tid >> 7;
        float posn = (float)(st * 128 + srow) * (1.0f / 8192.0f);
        #pragma unroll
        for (int c = 0; c < 8; ++c) {
            int w0 = half * 64 + c * 8;
            f32x4 fa = *(const f32x4*)&pLDS[w0];
            f32x4 fb = *(const f32x4*)&pLDS[w0 + 4];
            f32x4 aa = *(const f32x4*)&pLDS[128 + w0];
            f32x4 ab = *(const f32x4*)&pLDS[128 + w0 + 4];
            f32x4 pa = *(const f32x4*)&pLDS[256 + w0];
            f32x4 pb = *(const f32x4*)&pLDS[256 + w0 + 4];
            bf16x8 pk;
            #pragma unroll
            for (int j = 0; j < 4; ++j)
                pk[j] = f2bf(aa[j] * sin2pi(fa[j] * posn + pa[j]));
            #pragma unroll
            for (int j = 0; j < 4; ++j)
                pk[4 + j] = f2bf(ab[j] * sin2pi(fb[j] * posn + pb[j]));
            *(bf16x8*)&waveLDS[srow * NW + (w0 ^ ((srow & 7) << 3))] = pk;
        }
    }
    __syncthreads();

    f32x4 acc[4][4];
    #pragma unroll
    for (int mi = 0; mi < 4; ++mi)
        #pragma unroll
        for (int ni = 0; ni < 4; ++ni)
            acc[mi][ni] = (f32x4){0.f, 0.f, 0.f, 0.f};

    const short* wdfF = wdf + (size_t)f * 16384;
    #pragma unroll
    for (int ks = 0; ks < 4; ++ks) {
        bf16x8 bfr[4];
        #pragma unroll
        for (int ni = 0; ni < 4; ++ni) {
            int nt = wc * 4 + ni;
            bfr[ni] = *(const bf16x8*)(wdfF + ((size_t)((nt * 4 + ks) * 64 + lane)) * 8);
        }
        bf16x8 afr[4];
        #pragma unroll
        for (int mi = 0; mi < 4; ++mi) {
            int row = wr * 64 + mi * 16 + rlo;
            int col = ks * 32 + rgrp * 8;
            afr[mi] = *(const bf16x8*)&waveLDS[row * NW + (col ^ ((row & 7) << 3))];
        }
        #pragma unroll
        for (int mi = 0; mi < 4; ++mi)
            #pragma unroll
            for (int ni = 0; ni < 4; ++ni)
                acc[mi][ni] = __builtin_amdgcn_mfma_f32_16x16x32_bf16(afr[mi], bfr[ni], acc[mi][ni], 0, 0, 0);
    }

    size_t base = ((size_t)f * NS + (size_t)st * 128) * ND;
    #pragma unroll
    for (int mi = 0; mi < 4; ++mi) {
        #pragma unroll
        for (int r = 0; r < 4; ++r) {
            int sl = wr * 64 + mi * 16 + rgrp * 4 + r;
            float* dst = out + base + (size_t)sl * ND + wc * 64 + rlo;
            #pragma unroll
            for (int ni = 0; ni < 4; ++ni)
                dst[ni * 16] = acc[mi][ni][r];
        }
    }
}

extern "C" void kernel_launch(void* const* d_in, const int* in_sizes, int n_in,
                              void* d_out, int out_size, void* d_ws, size_t ws_size,
                              hipStream_t stream) {
    const float* kv    = (const float*)d_in[0];
    // d_in[1] = positions (arange, encoded analytically)
    const float* Wenc  = (const float*)d_in[2];
    const float* Wdec  = (const float*)d_in[3];
    const float* bfreq = (const float*)d_in[4];

    float* wpar = (float*)d_ws;                         // 3*64*128 floats = 96 KB
    short* wdf  = (short*)((char*)d_ws + 98304);        // 64*16384 bf16 = 2 MB

    wf_wdec   <<<dim3(NF, 8), 256, 0, stream>>>(Wdec, wdf);
    wf_stage_a<<<dim3(NF, 6), 256, 0, stream>>>(kv, Wenc, bfreq, wpar);
    wf_stage_b<<<dim3(NS / 128, NF), 256, 0, stream>>>(wpar, wdf, (float*)d_out);
}